// Round 1
// baseline (2486.568 us; speedup 1.0000x reference)
//
#include <hip/hip_runtime.h>

namespace {

constexpr int T_ = 16;
constexpr int F_ = 256;
constexpr int QLD = 772;   // padded LDS row stride (floats) for QKV: breaks i*768%32==0 bank aliasing

__device__ __forceinline__ float sm_at(int i) {
  // SAMPLE_MASKS = {0,1,3,4,7,9,12,14,17,19,23,26,28,31,35,38}
  float r = 0.0f;
  r = (i == 1)  ? 1.0f  : r;
  r = (i == 2)  ? 3.0f  : r;
  r = (i == 3)  ? 4.0f  : r;
  r = (i == 4)  ? 7.0f  : r;
  r = (i == 5)  ? 9.0f  : r;
  r = (i == 6)  ? 12.0f : r;
  r = (i == 7)  ? 14.0f : r;
  r = (i == 8)  ? 17.0f : r;
  r = (i == 9)  ? 19.0f : r;
  r = (i == 10) ? 23.0f : r;
  r = (i == 11) ? 26.0f : r;
  r = (i == 12) ? 28.0f : r;
  r = (i == 13) ? 31.0f : r;
  r = (i == 14) ? 35.0f : r;
  r = (i == 15) ? 38.0f : r;
  return r;
}

} // namespace

// lin_w [256][256] -> linT[f][e] = lin_w[e][f]  (so FF GEMM reads contiguous rows)
extern "C" __global__ void __launch_bounds__(256)
transpose_w(const float* __restrict__ w, float* __restrict__ wt) {
  __shared__ float tile[32][33];
  const int bx = blockIdx.x & 7;        // col tile of w
  const int by = blockIdx.x >> 3;       // row tile of w
  const int tx = threadIdx.x & 31;
  const int ty = threadIdx.x >> 5;      // 0..7
#pragma unroll
  for (int r = ty; r < 32; r += 8)
    tile[r][tx] = w[(by * 32 + r) * F_ + bx * 32 + tx];
  __syncthreads();
#pragma unroll
  for (int r = ty; r < 32; r += 8)
    wt[(bx * 32 + r) * F_ + by * 32 + tx] = tile[tx][r];
}

extern "C" __global__ void __launch_bounds__(256, 2)
fused_temporal_attn(const float* __restrict__ x, const float* __restrict__ pos_emb,
                    const float* __restrict__ Wq, const float* __restrict__ Wk,
                    const float* __restrict__ Wv, const float* __restrict__ linT,
                    const float* __restrict__ lin_b, float* __restrict__ out) {
  __shared__ float sTemp[T_][F_];    // temporal (kept for final residual)
  __shared__ float sQKV[T_][QLD];    // [ q(0:256) | k(256:512) | v(512:768) ]; q region reused for att_out

  const int n = blockIdx.x;
  const int tid = threadIdx.x;

  // ---------------- Phase 1: temporal = x + pos_emb ----------------
  {
    const float4* x4 = (const float4*)(x + (size_t)n * (T_ * F_));
    const float4* p4 = (const float4*)pos_emb;
    float4* sT4 = (float4*)(&sTemp[0][0]);
#pragma unroll
    for (int it = 0; it < 4; ++it) {
      const int idx = tid + it * 256;
      float4 a = x4[idx];
      const float4 b = p4[idx];
      a.x += b.x; a.y += b.y; a.z += b.z; a.w += b.w;
      sT4[idx] = a;
    }
  }
  __syncthreads();

  const int rg = tid >> 6;        // 0..3  (wave id -> row group; whole wave shares rows => LDS broadcast)
  const int cg = tid & 63;        // 0..63 (col group; contiguous float4 weight loads across the wave)
  const int r0 = rg << 2;
  const int c0 = cg << 2;

  // ---------------- Phase 2: QKV = temporal @ [Wq|Wk|Wv] ----------------
  {
    float aq[4][4], ak[4][4], av[4][4];
#pragma unroll
    for (int rr = 0; rr < 4; ++rr)
#pragma unroll
      for (int cc = 0; cc < 4; ++cc) { aq[rr][cc] = 0.f; ak[rr][cc] = 0.f; av[rr][cc] = 0.f; }

    const float* __restrict__ wqp = Wq + c0;
    const float* __restrict__ wkp = Wk + c0;
    const float* __restrict__ wvp = Wv + c0;

#pragma unroll 2
    for (int k = 0; k < F_; k += 4) {
      float a[4][4];
#pragma unroll
      for (int rr = 0; rr < 4; ++rr) {
        const float4 t4 = *(const float4*)&sTemp[r0 + rr][k];
        a[rr][0] = t4.x; a[rr][1] = t4.y; a[rr][2] = t4.z; a[rr][3] = t4.w;
      }
#pragma unroll
      for (int kk = 0; kk < 4; ++kk) {
        const float4 wq4 = *(const float4*)(wqp + (k + kk) * F_);
        const float4 wk4 = *(const float4*)(wkp + (k + kk) * F_);
        const float4 wv4 = *(const float4*)(wvp + (k + kk) * F_);
#pragma unroll
        for (int rr = 0; rr < 4; ++rr) {
          const float arr = a[rr][kk];
          aq[rr][0] = fmaf(arr, wq4.x, aq[rr][0]);
          aq[rr][1] = fmaf(arr, wq4.y, aq[rr][1]);
          aq[rr][2] = fmaf(arr, wq4.z, aq[rr][2]);
          aq[rr][3] = fmaf(arr, wq4.w, aq[rr][3]);
          ak[rr][0] = fmaf(arr, wk4.x, ak[rr][0]);
          ak[rr][1] = fmaf(arr, wk4.y, ak[rr][1]);
          ak[rr][2] = fmaf(arr, wk4.z, ak[rr][2]);
          ak[rr][3] = fmaf(arr, wk4.w, ak[rr][3]);
          av[rr][0] = fmaf(arr, wv4.x, av[rr][0]);
          av[rr][1] = fmaf(arr, wv4.y, av[rr][1]);
          av[rr][2] = fmaf(arr, wv4.z, av[rr][2]);
          av[rr][3] = fmaf(arr, wv4.w, av[rr][3]);
        }
      }
    }
#pragma unroll
    for (int rr = 0; rr < 4; ++rr) {
      *(float4*)&sQKV[r0 + rr][c0]          = make_float4(aq[rr][0], aq[rr][1], aq[rr][2], aq[rr][3]);
      *(float4*)&sQKV[r0 + rr][F_ + c0]     = make_float4(ak[rr][0], ak[rr][1], ak[rr][2], ak[rr][3]);
      *(float4*)&sQKV[r0 + rr][2 * F_ + c0] = make_float4(av[rr][0], av[rr][1], av[rr][2], av[rr][3]);
    }
  }
  __syncthreads();

  // ---------------- Phase 3: attention (thread = (head, query-row)) ----------------
  {
    const int h = tid >> 4;   // 0..15
    const int i = tid & 15;   // 0..15
    const float smi = sm_at(i);
    constexpr float SMV[16] = {0.f, 1.f, 3.f, 4.f, 7.f, 9.f, 12.f, 14.f,
                               17.f, 19.f, 23.f, 26.f, 28.f, 31.f, 35.f, 38.f};

    float qv[16];
#pragma unroll
    for (int dd = 0; dd < 4; ++dd) {
      const float4 q4 = *(const float4*)&sQKV[i][h * 16 + dd * 4];
      qv[4 * dd + 0] = q4.x; qv[4 * dd + 1] = q4.y; qv[4 * dd + 2] = q4.z; qv[4 * dd + 3] = q4.w;
    }

    float p[16];
    float mx = -3.0e38f;
#pragma unroll
    for (int j = 0; j < 16; ++j) {
      float dot = 0.f;
#pragma unroll
      for (int dd = 0; dd < 4; ++dd) {
        const float4 k4 = *(const float4*)&sQKV[j][F_ + h * 16 + dd * 4];
        dot = fmaf(qv[4 * dd + 0], k4.x, dot);
        dot = fmaf(qv[4 * dd + 1], k4.y, dot);
        dot = fmaf(qv[4 * dd + 2], k4.z, dot);
        dot = fmaf(qv[4 * dd + 3], k4.w, dot);
      }
      const float diff = (j < i) ? (smi - SMV[j]) : 1.0f;  // divisive temporal decay; diag/upper use 1
      float sc = (dot * 0.25f) / diff;                     // 1/sqrt(T) = 1/4
      sc = (j <= i) ? sc : -3.0e38f;                       // causal mask
      p[j] = sc;
      mx = fmaxf(mx, sc);
    }
    float den = 0.f;
#pragma unroll
    for (int j = 0; j < 16; ++j) {
      float e = __expf(p[j] - mx);
      e = (j <= i) ? e : 0.f;
      p[j] = e;
      den += e;
    }
    const float inv = 1.0f / den;

    float o[16];
#pragma unroll
    for (int d = 0; d < 16; ++d) o[d] = 0.f;
#pragma unroll
    for (int j = 0; j < 16; ++j) {
      const float pj = p[j] * inv;
#pragma unroll
      for (int dd = 0; dd < 4; ++dd) {
        const float4 v4 = *(const float4*)&sQKV[j][2 * F_ + h * 16 + dd * 4];
        o[4 * dd + 0] = fmaf(pj, v4.x, o[4 * dd + 0]);
        o[4 * dd + 1] = fmaf(pj, v4.y, o[4 * dd + 1]);
        o[4 * dd + 2] = fmaf(pj, v4.z, o[4 * dd + 2]);
        o[4 * dd + 3] = fmaf(pj, v4.w, o[4 * dd + 3]);
      }
    }
    __syncthreads();   // all q/k/v reads done before overwriting q region with att_out
#pragma unroll
    for (int dd = 0; dd < 4; ++dd)
      *(float4*)&sQKV[i][h * 16 + dd * 4] =
          make_float4(o[4 * dd + 0], o[4 * dd + 1], o[4 * dd + 2], o[4 * dd + 3]);
  }
  __syncthreads();

  // ---------------- Phase 4: FF + epilogue ----------------
  // out[i][e] = relu(sum_f att[i][f]*linT[f][e] + b[e]) + att[i][e] + temporal[i][e]
  {
    float acc[4][4];
#pragma unroll
    for (int rr = 0; rr < 4; ++rr)
#pragma unroll
      for (int cc = 0; cc < 4; ++cc) acc[rr][cc] = 0.f;

    const float* __restrict__ wtp = linT + c0;
#pragma unroll 2
    for (int k = 0; k < F_; k += 4) {
      float a[4][4];
#pragma unroll
      for (int rr = 0; rr < 4; ++rr) {
        const float4 t4 = *(const float4*)&sQKV[r0 + rr][k];   // att_out lives in q region
        a[rr][0] = t4.x; a[rr][1] = t4.y; a[rr][2] = t4.z; a[rr][3] = t4.w;
      }
#pragma unroll
      for (int kk = 0; kk < 4; ++kk) {
        const float4 w4 = *(const float4*)(wtp + (k + kk) * F_);
#pragma unroll
        for (int rr = 0; rr < 4; ++rr) {
          const float arr = a[rr][kk];
          acc[rr][0] = fmaf(arr, w4.x, acc[rr][0]);
          acc[rr][1] = fmaf(arr, w4.y, acc[rr][1]);
          acc[rr][2] = fmaf(arr, w4.z, acc[rr][2]);
          acc[rr][3] = fmaf(arr, w4.w, acc[rr][3]);
        }
      }
    }
    const float4 b4 = *(const float4*)(lin_b + c0);
    float* outp = out + (size_t)n * (T_ * F_);
#pragma unroll
    for (int rr = 0; rr < 4; ++rr) {
      const int r = r0 + rr;
      const float o0 = fmaxf(acc[rr][0] + b4.x, 0.f) + sQKV[r][c0 + 0] + sTemp[r][c0 + 0];
      const float o1 = fmaxf(acc[rr][1] + b4.y, 0.f) + sQKV[r][c0 + 1] + sTemp[r][c0 + 1];
      const float o2 = fmaxf(acc[rr][2] + b4.z, 0.f) + sQKV[r][c0 + 2] + sTemp[r][c0 + 2];
      const float o3 = fmaxf(acc[rr][3] + b4.w, 0.f) + sQKV[r][c0 + 3] + sTemp[r][c0 + 3];
      *(float4*)(outp + r * F_ + c0) = make_float4(o0, o1, o2, o3);
    }
  }
}

extern "C" void kernel_launch(void* const* d_in, const int* in_sizes, int n_in,
                              void* d_out, int out_size, void* d_ws, size_t ws_size,
                              hipStream_t stream) {
  const float* x   = (const float*)d_in[0];
  const float* pos = (const float*)d_in[1];
  const float* Wq  = (const float*)d_in[2];
  const float* Wk  = (const float*)d_in[3];
  const float* Wv  = (const float*)d_in[4];
  const float* lw  = (const float*)d_in[5];
  const float* lb  = (const float*)d_in[6];
  float* out  = (float*)d_out;
  float* linT = (float*)d_ws;   // 256 KB scratch for transposed lin_w

  transpose_w<<<64, 256, 0, stream>>>(lw, linT);
  fused_temporal_attn<<<16384, 256, 0, stream>>>(x, pos, Wq, Wk, Wv, linT, lb, out);
}

// Round 3
// 788.856 us; speedup vs baseline: 3.1521x; 3.1521x over previous
//
#include <hip/hip_runtime.h>

using short8  = __attribute__((ext_vector_type(8))) short;
using f32x4   = __attribute__((ext_vector_type(4))) float;

namespace {
constexpr int T_  = 16;
constexpr int F_  = 256;
constexpr int LDA = 260;   // sTemp stride (floats): 260 % 32 == 4 -> spreads banks
constexpr int QLD = 772;   // sQKV stride (floats): 772 % 32 == 4

__device__ __forceinline__ unsigned short f32_to_bf16_rn(float v) {
  unsigned u = __builtin_bit_cast(unsigned, v);
  unsigned r = u + 0x7FFFu + ((u >> 16) & 1u);
  return (unsigned short)(r >> 16);
}
// v ~= hi + lo with |err| ~ 2^-17 |v|
__device__ __forceinline__ void split_hi_lo(float v, unsigned short& h, unsigned short& l) {
  unsigned u = __builtin_bit_cast(unsigned, v);
  unsigned r = (u + 0x7FFFu + ((u >> 16) & 1u)) & 0xFFFF0000u;
  h = (unsigned short)(r >> 16);
  float lo = v - __builtin_bit_cast(float, r);
  l = f32_to_bf16_rn(lo);
}
} // namespace

// ---- prep: gather weights into MFMA B-fragment-linear bf16 chunks ----
// chunk (tile,s): 64 lanes x 8 bf16 = 1KB, lane l holds B[k = s*32+(l>>4)*8 + j][n = tile*16 + (l&15)]
// tiles 0..47: B = [Wq|Wk|Wv] (n = output feature col), k = input feature
// tiles 48..63: B[k=f][n=e] = lin_w[e][f]
extern "C" __global__ void __launch_bounds__(256)
build_frags(const float* __restrict__ Wq, const float* __restrict__ Wk,
            const float* __restrict__ Wv, const float* __restrict__ linw,
            unsigned short* __restrict__ frag) {
  const int g = blockIdx.x * 256 + threadIdx.x;   // 32768 threads total
  const int l = g & 63;
  const int chunk = g >> 6;                       // 0..511
  const int s = chunk & 7;
  const int tile = chunk >> 3;                    // 0..63
  const int lr = l & 15, lg = l >> 4;
  const int kbase = s * 32 + lg * 8;
  unsigned short v[8];
  if (tile < 48) {
    const int n = tile * 16 + lr;                 // 0..767
    const float* src = (n < 256) ? (Wq + n) : ((n < 512) ? (Wk + (n - 256)) : (Wv + (n - 512)));
#pragma unroll
    for (int j = 0; j < 8; ++j) v[j] = f32_to_bf16_rn(src[(kbase + j) * F_]);
  } else {
    const int e = (tile - 48) * 16 + lr;
    const float* src = linw + e * F_ + kbase;
#pragma unroll
    for (int j = 0; j < 8; ++j) v[j] = f32_to_bf16_rn(src[j]);
  }
  short8 pack;
#pragma unroll
  for (int j = 0; j < 8; ++j) pack[j] = (short)v[j];
  *(short8*)(frag + chunk * 512 + l * 8) = pack;
}

extern "C" __global__ void __launch_bounds__(256, 2)
fused_temporal_attn(const float* __restrict__ x, const float* __restrict__ pos_emb,
                    const unsigned short* __restrict__ frag,
                    const float* __restrict__ lin_b, float* __restrict__ out) {
  __shared__ float sTemp[T_][LDA];   // temporal fp32 (residual + QKV GEMM A-source)
  __shared__ float sQKV[T_][QLD];    // [q|k|v] fp32; q region reused for att_out

  const int n = blockIdx.x;
  const int tid = threadIdx.x;

  // ---------------- Phase 1: temporal = x + pos_emb ----------------
  {
    const float4* x4 = (const float4*)(x + (size_t)n * (T_ * F_));
    const float4* p4 = (const float4*)pos_emb;
#pragma unroll
    for (int it = 0; it < 4; ++it) {
      const int f4 = tid + it * 256;
      float4 a = x4[f4];
      const float4 b = p4[f4];
      a.x += b.x; a.y += b.y; a.z += b.z; a.w += b.w;
      const int row = f4 >> 6, c4 = f4 & 63;
      *(float4*)&sTemp[row][c4 * 4] = a;
    }
  }
  __syncthreads();

  const int wv = tid >> 6;   // wave 0..3
  const int l  = tid & 63;
  const int lr = l & 15;     // MFMA: A-row / B-col / C-col
  const int lg = l >> 4;     // MFMA: k-group / C row-group

  // ---------------- Phase 2: QKV = temporal @ [Wq|Wk|Wv] via MFMA ----------------
  // wave wv owns N-tiles wv*12 .. wv*12+11 (16 cols each) of the 768-wide output
  {
    f32x4 acc[12];
#pragma unroll
    for (int t = 0; t < 12; ++t) acc[t] = (f32x4){0.f, 0.f, 0.f, 0.f};

#pragma unroll 2
    for (int s = 0; s < 8; ++s) {
      const float* ap = &sTemp[lr][s * 32 + lg * 8];
      const float4 a0 = *(const float4*)ap;
      const float4 a1 = *(const float4*)(ap + 4);
      const float av[8] = {a0.x, a0.y, a0.z, a0.w, a1.x, a1.y, a1.z, a1.w};
      short8 ah, al;
#pragma unroll
      for (int j = 0; j < 8; ++j) {
        unsigned short hh, ll;
        split_hi_lo(av[j], hh, ll);
        ah[j] = (short)hh; al[j] = (short)ll;
      }
      const unsigned short* bp = frag + (size_t)((wv * 12) * 8 + s) * 512 + l * 8;
#pragma unroll
      for (int t = 0; t < 12; ++t) {
        const short8 b = *(const short8*)(bp + t * 4096);   // tile stride = 8 chunks * 512
        acc[t] = __builtin_amdgcn_mfma_f32_16x16x32_bf16(ah, b, acc[t], 0, 0, 0);
        acc[t] = __builtin_amdgcn_mfma_f32_16x16x32_bf16(al, b, acc[t], 0, 0, 0);
      }
    }
    // C layout: col = lr, row = lg*4 + reg
#pragma unroll
    for (int t = 0; t < 12; ++t) {
      const int col = (wv * 12 + t) * 16 + lr;
#pragma unroll
      for (int r = 0; r < 4; ++r) sQKV[lg * 4 + r][col] = acc[t][r];
    }
  }
  __syncthreads();

  // ---------------- Phase 3: attention (thread = (head, query-row)) — fp32, unchanged ----------------
  {
    const int h = tid >> 4;   // 0..15
    const int i = tid & 15;   // 0..15
    constexpr float SMV[16] = {0.f, 1.f, 3.f, 4.f, 7.f, 9.f, 12.f, 14.f,
                               17.f, 19.f, 23.f, 26.f, 28.f, 31.f, 35.f, 38.f};
    const float smi = SMV[i];

    float qv[16];
#pragma unroll
    for (int dd = 0; dd < 4; ++dd) {
      const float4 q4 = *(const float4*)&sQKV[i][h * 16 + dd * 4];
      qv[4 * dd + 0] = q4.x; qv[4 * dd + 1] = q4.y; qv[4 * dd + 2] = q4.z; qv[4 * dd + 3] = q4.w;
    }

    float p[16];
    float mx = -3.0e38f;
#pragma unroll
    for (int j = 0; j < 16; ++j) {
      float dot = 0.f;
#pragma unroll
      for (int dd = 0; dd < 4; ++dd) {
        const float4 k4 = *(const float4*)&sQKV[j][F_ + h * 16 + dd * 4];
        dot = fmaf(qv[4 * dd + 0], k4.x, dot);
        dot = fmaf(qv[4 * dd + 1], k4.y, dot);
        dot = fmaf(qv[4 * dd + 2], k4.z, dot);
        dot = fmaf(qv[4 * dd + 3], k4.w, dot);
      }
      const float diff = (j < i) ? (smi - SMV[j]) : 1.0f;
      float sc = (dot * 0.25f) / diff;
      sc = (j <= i) ? sc : -3.0e38f;
      p[j] = sc;
      mx = fmaxf(mx, sc);
    }
    float den = 0.f;
#pragma unroll
    for (int j = 0; j < 16; ++j) {
      float e = __expf(p[j] - mx);
      e = (j <= i) ? e : 0.f;
      p[j] = e;
      den += e;
    }
    const float inv = 1.0f / den;

    float o[16];
#pragma unroll
    for (int d = 0; d < 16; ++d) o[d] = 0.f;
#pragma unroll
    for (int j = 0; j < 16; ++j) {
      const float pj = p[j] * inv;
#pragma unroll
      for (int dd = 0; dd < 4; ++dd) {
        const float4 v4 = *(const float4*)&sQKV[j][2 * F_ + h * 16 + dd * 4];
        o[4 * dd + 0] = fmaf(pj, v4.x, o[4 * dd + 0]);
        o[4 * dd + 1] = fmaf(pj, v4.y, o[4 * dd + 1]);
        o[4 * dd + 2] = fmaf(pj, v4.z, o[4 * dd + 2]);
        o[4 * dd + 3] = fmaf(pj, v4.w, o[4 * dd + 3]);
      }
    }
    __syncthreads();   // all q/k/v reads done before overwriting q region with att_out
#pragma unroll
    for (int dd = 0; dd < 4; ++dd)
      *(float4*)&sQKV[i][h * 16 + dd * 4] =
          make_float4(o[4 * dd + 0], o[4 * dd + 1], o[4 * dd + 2], o[4 * dd + 3]);
  }
  __syncthreads();

  // ---------------- Phase 4: FF via MFMA + epilogue ----------------
  // wave wv owns N-tiles wv*4 .. wv*4+3 of the 256-wide FF output (frag tiles 48+)
  {
    f32x4 fa[4];
#pragma unroll
    for (int t = 0; t < 4; ++t) fa[t] = (f32x4){0.f, 0.f, 0.f, 0.f};

#pragma unroll 2
    for (int s = 0; s < 8; ++s) {
      const float* ap = &sQKV[lr][s * 32 + lg * 8];   // att_out lives in q region
      const float4 a0 = *(const float4*)ap;
      const float4 a1 = *(const float4*)(ap + 4);
      const float av[8] = {a0.x, a0.y, a0.z, a0.w, a1.x, a1.y, a1.z, a1.w};
      short8 ah, al;
#pragma unroll
      for (int j = 0; j < 8; ++j) {
        unsigned short hh, ll;
        split_hi_lo(av[j], hh, ll);
        ah[j] = (short)hh; al[j] = (short)ll;
      }
      const unsigned short* bp = frag + (size_t)((48 + wv * 4) * 8 + s) * 512 + l * 8;
#pragma unroll
      for (int t = 0; t < 4; ++t) {
        const short8 b = *(const short8*)(bp + t * 4096);
        fa[t] = __builtin_amdgcn_mfma_f32_16x16x32_bf16(ah, b, fa[t], 0, 0, 0);
        fa[t] = __builtin_amdgcn_mfma_f32_16x16x32_bf16(al, b, fa[t], 0, 0, 0);
      }
    }

    float* outp = out + (size_t)n * (T_ * F_);
#pragma unroll
    for (int t = 0; t < 4; ++t) {
      const int col = (wv * 4 + t) * 16 + lr;
      const float bias = lin_b[col];
#pragma unroll
      for (int r = 0; r < 4; ++r) {
        const int row = lg * 4 + r;
        const float val = fmaxf(fa[t][r] + bias, 0.f) + sQKV[row][col] + sTemp[row][col];
        outp[row * F_ + col] = val;
      }
    }
  }
}

extern "C" void kernel_launch(void* const* d_in, const int* in_sizes, int n_in,
                              void* d_out, int out_size, void* d_ws, size_t ws_size,
                              hipStream_t stream) {
  const float* x   = (const float*)d_in[0];
  const float* pos = (const float*)d_in[1];
  const float* Wq  = (const float*)d_in[2];
  const float* Wk  = (const float*)d_in[3];
  const float* Wv  = (const float*)d_in[4];
  const float* lw  = (const float*)d_in[5];
  const float* lb  = (const float*)d_in[6];
  float* out = (float*)d_out;
  unsigned short* frag = (unsigned short*)d_ws;   // 64 tiles * 8 ksteps * 1KB = 512 KB

  build_frags<<<128, 256, 0, stream>>>(Wq, Wk, Wv, lw, frag);
  fused_temporal_attn<<<16384, 256, 0, stream>>>(x, pos, frag, lb, out);
}